// Round 1
// baseline (5674.620 us; speedup 1.0000x reference)
//
#include <hip/hip_runtime.h>
#include <math.h>

#define N_RES 8192
#define N_IN  128
#define BATCH 16
#define LEAK  0.9f

// ---------------------------------------------------------------------------
// ws layout (total ~1.06 MB):
//   z       : [N_RES][BATCH] f32 accumulator        offset 0        (524288 B)
//   state_T : [N_RES][BATCH] f32 transposed state   offset 524288   (524288 B)
//   x_T     : [N_IN][BATCH]  f32 transposed x       offset 1048576  (8192 B)
// ---------------------------------------------------------------------------

__global__ __launch_bounds__(256) void transpose_kernel(
    const float* __restrict__ state,  // [BATCH][N_RES]
    const float* __restrict__ x,      // [BATCH][N_IN]
    float* __restrict__ state_T,      // [N_RES][BATCH]
    float* __restrict__ x_T) {        // [N_IN][BATCH]
  int tid = blockIdx.x * blockDim.x + threadIdx.x;
  if (tid < N_RES * BATCH) {
    int b = tid / N_RES;
    int r = tid - b * N_RES;
    state_T[r * BATCH + b] = state[tid];  // read coalesced, scatter write (small)
  }
  if (tid < N_IN * BATCH) {
    int b = tid / N_IN;
    int c = tid - b * N_IN;
    x_T[c * BATCH + b] = x[tid];
  }
}

// One thread per nnz: 3 scalar loads + 4x float4 gather (one 64B line) +
// 16 HW f32 atomics to one 64B line of z.
__global__ __launch_bounds__(256) void spmm_atomic(
    const float* __restrict__ vals,
    const int* __restrict__ rows,
    const int* __restrict__ cols,
    const float* __restrict__ srcT,   // [n_cols][BATCH]
    float* __restrict__ z,            // [N_RES][BATCH]
    int nnz) {
  int i = blockIdx.x * blockDim.x + threadIdx.x;
  if (i >= nnz) return;
  float v = vals[i];
  int r = rows[i];
  int c = cols[i];
  const float4* __restrict__ s4 = (const float4*)(srcT + c * BATCH);
  float* zr = z + r * BATCH;
#pragma unroll
  for (int q = 0; q < 4; ++q) {
    float4 s = s4[q];
    unsafeAtomicAdd(zr + q * 4 + 0, v * s.x);
    unsafeAtomicAdd(zr + q * 4 + 1, v * s.y);
    unsafeAtomicAdd(zr + q * 4 + 2, v * s.z);
    unsafeAtomicAdd(zr + q * 4 + 3, v * s.w);
  }
}

__global__ __launch_bounds__(256) void finalize_kernel(
    const float* __restrict__ z,        // [N_RES][BATCH]
    const float* __restrict__ state,    // [BATCH][N_RES]
    const float* __restrict__ res_bias, // [N_RES]
    const float* __restrict__ in_bias,  // [N_RES]
    float* __restrict__ out) {          // [BATCH][N_RES]
  int tid = blockIdx.x * blockDim.x + threadIdx.x;
  if (tid >= BATCH * N_RES) return;
  int b = tid >> 13;            // N_RES = 8192 = 2^13
  int r = tid & (N_RES - 1);
  float zz = z[r * BATCH + b] + res_bias[r] + in_bias[r];
  out[tid] = (1.0f - LEAK) * state[tid] + LEAK * erff(zz);
}

extern "C" void kernel_launch(void* const* d_in, const int* in_sizes, int n_in,
                              void* d_out, int out_size, void* d_ws, size_t ws_size,
                              hipStream_t stream) {
  const float* state    = (const float*)d_in[0];
  const float* x        = (const float*)d_in[1];
  const float* res_vals = (const float*)d_in[2];
  const int*   res_rows = (const int*)d_in[3];
  const int*   res_cols = (const int*)d_in[4];
  const float* res_bias = (const float*)d_in[5];
  const float* in_vals  = (const float*)d_in[6];
  const int*   in_rows  = (const int*)d_in[7];
  const int*   in_cols  = (const int*)d_in[8];
  const float* in_bias  = (const float*)d_in[9];

  const int res_nnz = in_sizes[2];
  const int in_nnz  = in_sizes[6];

  float* z       = (float*)d_ws;
  float* state_T = z + N_RES * BATCH;
  float* x_T     = state_T + N_RES * BATCH;
  float* out     = (float*)d_out;

  // Zero the accumulator (ws is poisoned 0xAA before every launch).
  hipMemsetAsync(z, 0, N_RES * BATCH * sizeof(float), stream);

  transpose_kernel<<<(N_RES * BATCH + 255) / 256, 256, 0, stream>>>(
      state, x, state_T, x_T);

  spmm_atomic<<<(res_nnz + 255) / 256, 256, 0, stream>>>(
      res_vals, res_rows, res_cols, state_T, z, res_nnz);

  spmm_atomic<<<(in_nnz + 255) / 256, 256, 0, stream>>>(
      in_vals, in_rows, in_cols, x_T, z, in_nnz);

  finalize_kernel<<<(BATCH * N_RES + 255) / 256, 256, 0, stream>>>(
      z, state, res_bias, in_bias, out);
}

// Round 2
// 728.877 us; speedup vs baseline: 7.7854x; 7.7854x over previous
//
#include <hip/hip_runtime.h>
#include <math.h>

#define N_RES 8192
#define N_IN  128
#define BATCH 16
#define LEAK  0.9f

#define NB   32        // row buckets
#define RPB  256       // rows per bucket (N_RES / NB)
#define CAP  229376    // entry capacity per bucket (exp ~213K, +24 sigma)
#define K2   32        // phase-2 blocks per bucket
#define EPT  16        // phase-1 entries per thread (4096 per 256-thread block)

// ws layout (bytes):
//   srcT     @ 0        : [8192+128][16] f32 concat transposed state|x (532480 B)
//   cursors  @ 1 MB     : int[NB]
//   partials @ 2 MB     : [NB][K2][RPB][BATCH] f32 = 16 MB
//   entries  @ 19 MB    : uint2[NB][CAP] = 58.7 MB
//   (fallback path: z @ 1 MB, srcT @ 0)
#define OFF_SRCT 0
#define OFF_CURS (1u << 20)
#define OFF_PART (2u << 20)
#define OFF_ENTR (19u << 20)
#define REQ_WS   (OFF_ENTR + (size_t)NB * CAP * 8)

// ---------------------------------------------------------------------------
__global__ __launch_bounds__(256) void transpose_kernel(
    const float* __restrict__ state,  // [BATCH][N_RES]
    const float* __restrict__ x,      // [BATCH][N_IN]
    float* __restrict__ srcT) {       // [8320][BATCH]
  int tid = blockIdx.x * 256 + threadIdx.x;
  if (tid < N_RES * BATCH) {
    int b = tid >> 13;            // N_RES = 2^13
    int r = tid & (N_RES - 1);
    srcT[r * BATCH + b] = state[tid];
  }
  if (tid < N_IN * BATCH) {
    int b = tid >> 7;             // N_IN = 2^7
    int c = tid & (N_IN - 1);
    srcT[(N_RES + c) * BATCH + b] = x[tid];
  }
}

// ---------------------------------------------------------------------------
// Phase 1: pack nnz into row buckets with block-aggregated cursor reservation.
__global__ __launch_bounds__(256) void scatter_kernel(
    const float* __restrict__ vals,
    const int* __restrict__ rows,
    const int* __restrict__ cols,
    int nnz, int col_off,
    uint2* __restrict__ entries,      // [NB][CAP]
    int* __restrict__ cursors) {      // [NB]
  __shared__ int lcount[NB];
  __shared__ int lbase[NB];
  int tid = threadIdx.x;
  if (tid < NB) lcount[tid] = 0;
  __syncthreads();

  int base = blockIdx.x * (256 * EPT);
  float v[EPT];
  unsigned a[EPT];
  int bk[EPT];
#pragma unroll
  for (int e = 0; e < EPT; ++e) {
    int i = base + e * 256 + tid;
    bk[e] = -1;
    if (i < nnz) {
      int r = rows[i];
      int c = cols[i];
      v[e] = vals[i];
      bk[e] = r >> 8;
      a[e] = ((unsigned)(r & (RPB - 1)) << 14) | (unsigned)(c + col_off);
      atomicAdd(&lcount[bk[e]], 1);
    }
  }
  __syncthreads();
  if (tid < NB) {
    int c = lcount[tid];
    lbase[tid] = (c > 0) ? atomicAdd(&cursors[tid], c) : 0;
    lcount[tid] = 0;  // reuse as intra-block cursor
  }
  __syncthreads();
#pragma unroll
  for (int e = 0; e < EPT; ++e) {
    if (bk[e] >= 0) {
      int pos = lbase[bk[e]] + atomicAdd(&lcount[bk[e]], 1);
      if (pos < CAP)
        entries[(size_t)bk[e] * CAP + pos] = make_uint2(__float_as_uint(v[e]), a[e]);
    }
  }
}

// ---------------------------------------------------------------------------
// Phase 2: per-bucket LDS accumulation. 16 lanes per entry (batch on lanes).
__global__ __launch_bounds__(256) void accum_kernel(
    const uint2* __restrict__ entries,
    const int* __restrict__ cursors,
    const float* __restrict__ srcT,     // [8320][BATCH]
    float* __restrict__ partials) {     // [NB][K2][RPB][BATCH]
  int bucket = blockIdx.x / K2;
  int k = blockIdx.x - bucket * K2;
  __shared__ float tile[RPB * BATCH];   // 16 KB
  int tid = threadIdx.x;
#pragma unroll
  for (int i = tid; i < RPB * BATCH; i += 256) tile[i] = 0.0f;
  __syncthreads();

  int count = cursors[bucket];
  if (count > CAP) count = CAP;
  int start = (int)((long long)count * k / K2);
  int end   = (int)((long long)count * (k + 1) / K2);
  const uint2* __restrict__ eb = entries + (size_t)bucket * CAP;
  int lane_b = tid & (BATCH - 1);
  int group = tid >> 4;                 // 16 entries per block-iteration

  for (int e = start + group; e < end; e += 16) {
    uint2 ld = eb[e];
    float vv = __uint_as_float(ld.x);
    unsigned aux = ld.y;
    int col = aux & 16383;
    int rl = aux >> 14;
    float s = srcT[col * BATCH + lane_b];
    atomicAdd(&tile[rl * BATCH + lane_b], vv * s);
  }
  __syncthreads();

  float* __restrict__ pb = partials + ((size_t)bucket * K2 + k) * (RPB * BATCH);
#pragma unroll
  for (int i = tid; i < RPB * BATCH; i += 256) pb[i] = tile[i];
}

// ---------------------------------------------------------------------------
// Reduce K2 partials, add biases, erf, leaky mix.  thread = r*16 + b.
__global__ __launch_bounds__(256) void finalize_kernel(
    const float* __restrict__ partials,
    const float* __restrict__ state,     // [BATCH][N_RES]
    const float* __restrict__ res_bias,
    const float* __restrict__ in_bias,
    float* __restrict__ out) {           // [BATCH][N_RES]
  int tid = blockIdx.x * 256 + threadIdx.x;
  if (tid >= N_RES * BATCH) return;
  int b = tid & (BATCH - 1);
  int r = tid >> 4;
  int bucket = r >> 8;
  int rl = r & (RPB - 1);
  const float* __restrict__ p =
      partials + (size_t)bucket * K2 * (RPB * BATCH) + rl * BATCH + b;
  float z = 0.0f;
#pragma unroll
  for (int k = 0; k < K2; ++k) z += p[(size_t)k * (RPB * BATCH)];
  z += res_bias[r] + in_bias[r];
  int idx = b * N_RES + r;
  out[idx] = (1.0f - LEAK) * state[idx] + LEAK * erff(z);
}

// ---------------------------------------------------------------------------
// Fallback (ws too small): round-1 atomic path.
__global__ __launch_bounds__(256) void spmm_atomic(
    const float* __restrict__ vals,
    const int* __restrict__ rows,
    const int* __restrict__ cols,
    const float* __restrict__ srcT, int col_off,
    float* __restrict__ z, int nnz) {
  int i = blockIdx.x * blockDim.x + threadIdx.x;
  if (i >= nnz) return;
  float v = vals[i];
  int r = rows[i];
  int c = cols[i] + col_off;
  const float4* __restrict__ s4 = (const float4*)(srcT + c * BATCH);
  float* zr = z + r * BATCH;
#pragma unroll
  for (int q = 0; q < 4; ++q) {
    float4 s = s4[q];
    unsafeAtomicAdd(zr + q * 4 + 0, v * s.x);
    unsafeAtomicAdd(zr + q * 4 + 1, v * s.y);
    unsafeAtomicAdd(zr + q * 4 + 2, v * s.z);
    unsafeAtomicAdd(zr + q * 4 + 3, v * s.w);
  }
}

__global__ __launch_bounds__(256) void finalize_z_kernel(
    const float* __restrict__ z,         // [N_RES][BATCH]
    const float* __restrict__ state,
    const float* __restrict__ res_bias,
    const float* __restrict__ in_bias,
    float* __restrict__ out) {
  int tid = blockIdx.x * 256 + threadIdx.x;
  if (tid >= BATCH * N_RES) return;
  int b = tid >> 13;
  int r = tid & (N_RES - 1);
  float zz = z[r * BATCH + b] + res_bias[r] + in_bias[r];
  out[tid] = (1.0f - LEAK) * state[tid] + LEAK * erff(zz);
}

// ---------------------------------------------------------------------------
extern "C" void kernel_launch(void* const* d_in, const int* in_sizes, int n_in,
                              void* d_out, int out_size, void* d_ws, size_t ws_size,
                              hipStream_t stream) {
  const float* state    = (const float*)d_in[0];
  const float* x        = (const float*)d_in[1];
  const float* res_vals = (const float*)d_in[2];
  const int*   res_rows = (const int*)d_in[3];
  const int*   res_cols = (const int*)d_in[4];
  const float* res_bias = (const float*)d_in[5];
  const float* in_vals  = (const float*)d_in[6];
  const int*   in_rows  = (const int*)d_in[7];
  const int*   in_cols  = (const int*)d_in[8];
  const float* in_bias  = (const float*)d_in[9];

  const int res_nnz = in_sizes[2];
  const int in_nnz  = in_sizes[6];

  char* ws = (char*)d_ws;
  float* srcT = (float*)(ws + OFF_SRCT);
  float* out = (float*)d_out;

  if (ws_size >= REQ_WS) {
    int* cursors = (int*)(ws + OFF_CURS);
    float* partials = (float*)(ws + OFF_PART);
    uint2* entries = (uint2*)(ws + OFF_ENTR);

    hipMemsetAsync(cursors, 0, NB * sizeof(int), stream);
    transpose_kernel<<<(N_RES * BATCH + 255) / 256, 256, 0, stream>>>(state, x, srcT);

    scatter_kernel<<<(res_nnz + 256 * EPT - 1) / (256 * EPT), 256, 0, stream>>>(
        res_vals, res_rows, res_cols, res_nnz, 0, entries, cursors);
    scatter_kernel<<<(in_nnz + 256 * EPT - 1) / (256 * EPT), 256, 0, stream>>>(
        in_vals, in_rows, in_cols, in_nnz, N_RES, entries, cursors);

    accum_kernel<<<NB * K2, 256, 0, stream>>>(entries, cursors, srcT, partials);

    finalize_kernel<<<(N_RES * BATCH + 255) / 256, 256, 0, stream>>>(
        partials, state, res_bias, in_bias, out);
  } else {
    // Fallback: atomic path (correct, slow).
    float* z = (float*)(ws + OFF_CURS);  // 512 KB @ 1 MB offset
    hipMemsetAsync(z, 0, N_RES * BATCH * sizeof(float), stream);
    transpose_kernel<<<(N_RES * BATCH + 255) / 256, 256, 0, stream>>>(state, x, srcT);
    spmm_atomic<<<(res_nnz + 255) / 256, 256, 0, stream>>>(
        res_vals, res_rows, res_cols, srcT, 0, z, res_nnz);
    spmm_atomic<<<(in_nnz + 255) / 256, 256, 0, stream>>>(
        in_vals, in_rows, in_cols, srcT, N_RES, z, in_nnz);
    finalize_z_kernel<<<(BATCH * N_RES + 255) / 256, 256, 0, stream>>>(
        z, state, res_bias, in_bias, out);
  }
}

// Round 3
// 720.424 us; speedup vs baseline: 7.8768x; 1.0117x over previous
//
#include <hip/hip_runtime.h>
#include <math.h>

#define N_RES 8192
#define N_IN  128
#define BATCH 16
#define LEAK  0.9f

#define NB   32        // row buckets
#define RPB  256       // rows per bucket (N_RES / NB)
#define CAP  229376    // entry capacity per bucket (exp ~213K, +24 sigma)
#define K2   32        // phase-2 blocks per bucket
#define EPT  16        // phase-1 entries per thread (4096 per 256-thread block)
#define UNR  8         // phase-2 unroll depth (entries in flight per group)

// ws layout (bytes):
//   srcT     @ 0        : [8192+128][16] f32 concat transposed state|x (532480 B)
//   cursors  @ 1 MB     : int[NB]
//   partials @ 2 MB     : [NB][K2][RPB][BATCH] f32 = 16 MB
//   entries  @ 19 MB    : uint2[NB][CAP] = 58.7 MB
#define OFF_SRCT 0
#define OFF_CURS (1u << 20)
#define OFF_PART (2u << 20)
#define OFF_ENTR (19u << 20)
#define REQ_WS   (OFF_ENTR + (size_t)NB * CAP * 8)

// ---------------------------------------------------------------------------
__global__ __launch_bounds__(256) void transpose_kernel(
    const float* __restrict__ state,  // [BATCH][N_RES]
    const float* __restrict__ x,      // [BATCH][N_IN]
    float* __restrict__ srcT) {       // [8320][BATCH]
  int tid = blockIdx.x * 256 + threadIdx.x;
  if (tid < N_RES * BATCH) {
    int b = tid >> 13;            // N_RES = 2^13
    int r = tid & (N_RES - 1);
    srcT[r * BATCH + b] = state[tid];
  }
  if (tid < N_IN * BATCH) {
    int b = tid >> 7;             // N_IN = 2^7
    int c = tid & (N_IN - 1);
    srcT[(N_RES + c) * BATCH + b] = x[tid];
  }
}

// ---------------------------------------------------------------------------
// Phase 1: pack nnz into row buckets with block-aggregated cursor reservation.
__global__ __launch_bounds__(256) void scatter_kernel(
    const float* __restrict__ vals,
    const int* __restrict__ rows,
    const int* __restrict__ cols,
    int nnz, int col_off,
    uint2* __restrict__ entries,      // [NB][CAP]
    int* __restrict__ cursors) {      // [NB]
  __shared__ int lcount[NB];
  __shared__ int lbase[NB];
  int tid = threadIdx.x;
  if (tid < NB) lcount[tid] = 0;
  __syncthreads();

  int base = blockIdx.x * (256 * EPT);
  float v[EPT];
  unsigned a[EPT];
  int bk[EPT];
#pragma unroll
  for (int e = 0; e < EPT; ++e) {
    int i = base + e * 256 + tid;
    bk[e] = -1;
    if (i < nnz) {
      int r = rows[i];
      int c = cols[i];
      v[e] = vals[i];
      bk[e] = r >> 8;
      a[e] = ((unsigned)(r & (RPB - 1)) << 14) | (unsigned)(c + col_off);
      atomicAdd(&lcount[bk[e]], 1);
    }
  }
  __syncthreads();
  if (tid < NB) {
    int c = lcount[tid];
    lbase[tid] = (c > 0) ? atomicAdd(&cursors[tid], c) : 0;
    lcount[tid] = 0;  // reuse as intra-block cursor
  }
  __syncthreads();
#pragma unroll
  for (int e = 0; e < EPT; ++e) {
    if (bk[e] >= 0) {
      int pos = lbase[bk[e]] + atomicAdd(&lcount[bk[e]], 1);
      if (pos < CAP)
        entries[(size_t)bk[e] * CAP + pos] = make_uint2(__float_as_uint(v[e]), a[e]);
    }
  }
}

// ---------------------------------------------------------------------------
// Phase 2: per-bucket LDS accumulation. 16 lanes per entry (batch on lanes).
// UNR-deep software pipeline: load UNR entry records, then decode + gather +
// ds_add as independent chains so UNR loads are in flight at both HBM (entry
// stream) and L2 (srcT gather) levels.
__global__ __launch_bounds__(256) void accum_kernel(
    const uint2* __restrict__ entries,
    const int* __restrict__ cursors,
    const float* __restrict__ srcT,     // [8320][BATCH]
    float* __restrict__ partials) {     // [NB][K2][RPB][BATCH]
  int bucket = blockIdx.x / K2;
  int k = blockIdx.x - bucket * K2;
  __shared__ float tile[RPB * BATCH];   // 16 KB
  int tid = threadIdx.x;
#pragma unroll
  for (int i = tid; i < RPB * BATCH; i += 256) tile[i] = 0.0f;
  __syncthreads();

  int count = cursors[bucket];
  if (count > CAP) count = CAP;
  int start = (int)((long long)count * k / K2);
  int end   = (int)((long long)count * (k + 1) / K2);
  const uint2* __restrict__ eb = entries + (size_t)bucket * CAP;
  int lane_b = tid & (BATCH - 1);
  int group = tid >> 4;                 // 16 groups; each handles one entry/slot

  int e = start + group;
  // Main unrolled loop: 16*UNR entries per block-iteration.
  for (; e + 16 * (UNR - 1) < end; e += 16 * UNR) {
    uint2 ld[UNR];
#pragma unroll
    for (int u = 0; u < UNR; ++u) ld[u] = eb[e + 16 * u];
    float vv[UNR], s[UNR];
    int rl[UNR];
#pragma unroll
    for (int u = 0; u < UNR; ++u) {
      vv[u] = __uint_as_float(ld[u].x);
      unsigned aux = ld[u].y;
      int col = aux & 16383;
      rl[u] = aux >> 14;
      s[u] = srcT[col * BATCH + lane_b];   // UNR independent L2 gathers
    }
#pragma unroll
    for (int u = 0; u < UNR; ++u)
      atomicAdd(&tile[rl[u] * BATCH + lane_b], vv[u] * s[u]);
  }
  // Tail.
  for (; e < end; e += 16) {
    uint2 ld = eb[e];
    float vv = __uint_as_float(ld.x);
    unsigned aux = ld.y;
    int col = aux & 16383;
    int rl = aux >> 14;
    float s = srcT[col * BATCH + lane_b];
    atomicAdd(&tile[rl * BATCH + lane_b], vv * s);
  }
  __syncthreads();

  float* __restrict__ pb = partials + ((size_t)bucket * K2 + k) * (RPB * BATCH);
#pragma unroll
  for (int i = tid; i < RPB * BATCH; i += 256) pb[i] = tile[i];
}

// ---------------------------------------------------------------------------
// Reduce K2 partials, add biases, erf, leaky mix.  thread = r*16 + b.
__global__ __launch_bounds__(256) void finalize_kernel(
    const float* __restrict__ partials,
    const float* __restrict__ state,     // [BATCH][N_RES]
    const float* __restrict__ res_bias,
    const float* __restrict__ in_bias,
    float* __restrict__ out) {           // [BATCH][N_RES]
  int tid = blockIdx.x * 256 + threadIdx.x;
  if (tid >= N_RES * BATCH) return;
  int b = tid & (BATCH - 1);
  int r = tid >> 4;
  int bucket = r >> 8;
  int rl = r & (RPB - 1);
  const float* __restrict__ p =
      partials + (size_t)bucket * K2 * (RPB * BATCH) + rl * BATCH + b;
  float z = 0.0f;
#pragma unroll
  for (int k = 0; k < K2; ++k) z += p[(size_t)k * (RPB * BATCH)];
  z += res_bias[r] + in_bias[r];
  int idx = b * N_RES + r;
  out[idx] = (1.0f - LEAK) * state[idx] + LEAK * erff(z);
}

// ---------------------------------------------------------------------------
// Fallback (ws too small): round-1 atomic path.
__global__ __launch_bounds__(256) void spmm_atomic(
    const float* __restrict__ vals,
    const int* __restrict__ rows,
    const int* __restrict__ cols,
    const float* __restrict__ srcT, int col_off,
    float* __restrict__ z, int nnz) {
  int i = blockIdx.x * blockDim.x + threadIdx.x;
  if (i >= nnz) return;
  float v = vals[i];
  int r = rows[i];
  int c = cols[i] + col_off;
  const float4* __restrict__ s4 = (const float4*)(srcT + c * BATCH);
  float* zr = z + r * BATCH;
#pragma unroll
  for (int q = 0; q < 4; ++q) {
    float4 s = s4[q];
    unsafeAtomicAdd(zr + q * 4 + 0, v * s.x);
    unsafeAtomicAdd(zr + q * 4 + 1, v * s.y);
    unsafeAtomicAdd(zr + q * 4 + 2, v * s.z);
    unsafeAtomicAdd(zr + q * 4 + 3, v * s.w);
  }
}

__global__ __launch_bounds__(256) void finalize_z_kernel(
    const float* __restrict__ z,         // [N_RES][BATCH]
    const float* __restrict__ state,
    const float* __restrict__ res_bias,
    const float* __restrict__ in_bias,
    float* __restrict__ out) {
  int tid = blockIdx.x * 256 + threadIdx.x;
  if (tid >= BATCH * N_RES) return;
  int b = tid >> 13;
  int r = tid & (N_RES - 1);
  float zz = z[r * BATCH + b] + res_bias[r] + in_bias[r];
  out[tid] = (1.0f - LEAK) * state[tid] + LEAK * erff(zz);
}

// ---------------------------------------------------------------------------
extern "C" void kernel_launch(void* const* d_in, const int* in_sizes, int n_in,
                              void* d_out, int out_size, void* d_ws, size_t ws_size,
                              hipStream_t stream) {
  const float* state    = (const float*)d_in[0];
  const float* x        = (const float*)d_in[1];
  const float* res_vals = (const float*)d_in[2];
  const int*   res_rows = (const int*)d_in[3];
  const int*   res_cols = (const int*)d_in[4];
  const float* res_bias = (const float*)d_in[5];
  const float* in_vals  = (const float*)d_in[6];
  const int*   in_rows  = (const int*)d_in[7];
  const int*   in_cols  = (const int*)d_in[8];
  const float* in_bias  = (const float*)d_in[9];

  const int res_nnz = in_sizes[2];
  const int in_nnz  = in_sizes[6];

  char* ws = (char*)d_ws;
  float* srcT = (float*)(ws + OFF_SRCT);
  float* out = (float*)d_out;

  if (ws_size >= REQ_WS) {
    int* cursors = (int*)(ws + OFF_CURS);
    float* partials = (float*)(ws + OFF_PART);
    uint2* entries = (uint2*)(ws + OFF_ENTR);

    hipMemsetAsync(cursors, 0, NB * sizeof(int), stream);
    transpose_kernel<<<(N_RES * BATCH + 255) / 256, 256, 0, stream>>>(state, x, srcT);

    scatter_kernel<<<(res_nnz + 256 * EPT - 1) / (256 * EPT), 256, 0, stream>>>(
        res_vals, res_rows, res_cols, res_nnz, 0, entries, cursors);
    scatter_kernel<<<(in_nnz + 256 * EPT - 1) / (256 * EPT), 256, 0, stream>>>(
        in_vals, in_rows, in_cols, in_nnz, N_RES, entries, cursors);

    accum_kernel<<<NB * K2, 256, 0, stream>>>(entries, cursors, srcT, partials);

    finalize_kernel<<<(N_RES * BATCH + 255) / 256, 256, 0, stream>>>(
        partials, state, res_bias, in_bias, out);
  } else {
    // Fallback: atomic path (correct, slow).
    float* z = (float*)(ws + OFF_CURS);  // 512 KB @ 1 MB offset
    hipMemsetAsync(z, 0, N_RES * BATCH * sizeof(float), stream);
    transpose_kernel<<<(N_RES * BATCH + 255) / 256, 256, 0, stream>>>(state, x, srcT);
    spmm_atomic<<<(res_nnz + 255) / 256, 256, 0, stream>>>(
        res_vals, res_rows, res_cols, srcT, 0, z, res_nnz);
    spmm_atomic<<<(in_nnz + 255) / 256, 256, 0, stream>>>(
        in_vals, in_rows, in_cols, srcT, N_RES, z, in_nnz);
    finalize_z_kernel<<<(BATCH * N_RES + 255) / 256, 256, 0, stream>>>(
        z, state, res_bias, in_bias, out);
  }
}